// Round 4
// baseline (17114.183 us; speedup 1.0000x reference)
//
#include <hip/hip_runtime.h>
#include <cstdint>
#include <cmath>

// ============================================================================
// Bidirectional 2-layer GRU, B=64 S=1024 I=H=512, output = last-step concat @ fc.
//   forward : 1024-step recurrence, persistent kernel, 64 blocks (2 layers x
//             32 col-slices), block = 64 rows x 16 cols, gates in-register.
//   backward: only scan index 0 survives => ONE step per layer with h0=0.
//
// Round-4 change: NO fences / cache-maintenance ops anywhere in the loop.
// All cross-block traffic (h planes, flags) uses relaxed AGENT-scope atomic
// loads/stores, which compile to sc0|sc1 global ops that bypass the
// non-coherent per-XCD L2 and serialize at the memory-side coherence point.
// Producer order: h stores -> s_waitcnt vmcnt(0) -> __syncthreads -> flag
// fetch_max. Consumer order: poll flag (branch dependency) -> h loads.
// Sticky timeout poison keeps the kernel hang-proof.
// ============================================================================

typedef __attribute__((ext_vector_type(8))) short bf16x8;
typedef __attribute__((ext_vector_type(4))) float f32x4;
typedef __attribute__((ext_vector_type(4))) unsigned int u32x4;

#define DEV static __device__ __forceinline__

DEV unsigned short f2bf(float f) {
  union { float f; uint32_t u; } v; v.f = f;
  uint32_t u = v.u;
  return (unsigned short)((u + (((u >> 16) & 1u) + 0x7fffu)) >> 16);
}
DEV float bf2f(unsigned short h) {
  union { uint32_t u; float f; } v; v.u = ((uint32_t)h) << 16;
  return v.f;
}
DEV float fsig(float x)  { return 1.f / (1.f + __expf(-x)); }
DEV float ftanh(float x) { return 2.f / (1.f + __expf(-2.f * x)) - 1.f; }

static constexpr int Ss = 1024, Ii = 512;

// ---- workspace layout (bytes) ----
static constexpr size_t WIMG_PER_LS = 131072;                  // 96KB hi + 32KB n-lo
static constexpr size_t OFF_WIMG = 0;
static constexpr size_t WIMG_BYTES = (size_t)64 * WIMG_PER_LS; // 8 MB
static constexpr size_t OFF_H1  = OFF_WIMG + WIMG_BYTES;       // 4 planes x (hi|lo) [64][512] bf16
static constexpr size_t OFF_H2  = OFF_H1 + 524288;
static constexpr size_t OFF_FLG = OFF_H2 + 524288;             // int[64] (+pad)
static constexpr size_t OFF_H2F = OFF_FLG + 1024;              // f32 [64][512]
static constexpr size_t OFF_HB1 = OFF_H2F + 131072;
static constexpr size_t OFF_HB2 = OFF_HB1 + 131072;
static constexpr size_t WS_NEED = OFF_HB2 + 131072;

// ============================================================================
// Weight prep (layout unchanged): per (layer,slice) 65536 bf16:
//   [0,49152)     hi : m(2:Wi,Wh)*24576 + kg(64)*384 + (g*16+cc)*8 + kr(8)
//   [49152,65536) n-gate lo residual: m*8192 + kg*128 + cc*8 + kr
// ============================================================================
__global__ __launch_bounds__(256) void prep_weights(const float* __restrict__ Wi,
                                                    const float* __restrict__ Wh,
                                                    unsigned short* __restrict__ img) {
  uint32_t idx = blockIdx.x * 256 + threadIdx.x;          // < 4,194,304
  uint32_t ls = idx >> 16;                                // layer*32+slice
  uint32_t off = idx & 65535u;
  int l = (int)(ls >> 5), s = (int)(ls & 31);
  int m, g, cc, kg, kr;
  bool lo = off >= 49152u;
  if (!lo) {
    m = (int)(off / 24576u); uint32_t r = off % 24576u;
    kg = (int)(r / 384u); r %= 384u;
    int c = (int)(r >> 3); kr = (int)(r & 7u);
    g = c >> 4; cc = c & 15;
  } else {
    uint32_t o2 = off - 49152u;
    m = (int)(o2 >> 13); uint32_t r = o2 & 8191u;
    kg = (int)(r >> 7); r &= 127u;
    cc = (int)(r >> 3); kr = (int)(r & 7u);
    g = 2;
  }
  int h = s * 16 + cc, k = kg * 8 + kr;
  const float* W = m ? Wh : Wi;                           // [L][D][3][512][512], d=0
  float v = W[((size_t)(l * 6 + g) * 512 + k) * 512 + h];
  unsigned short hv = f2bf(v);
  if (lo) hv = f2bf(v - bf2f(hv));
  img[(size_t)ls * 65536 + off] = hv;
}

// zero h rings; flags: layer0 = 0, layer1 = 1 (its step-1 is a virtual no-op)
__global__ __launch_bounds__(256) void init_state(uint32_t* __restrict__ hz,
                                                  int* __restrict__ flg) {
  int tid = blockIdx.x * 256 + threadIdx.x;
  if (tid < 262144) hz[tid] = 0u;                         // h1+h2 = 1MB
  if (tid < 64) flg[tid] = (tid >= 32) ? 1 : 0;
}

#define MFMA(AA, BB, CC) CC = __builtin_amdgcn_mfma_f32_16x16x32_bf16(AA, BB, CC, 0, 0, 0)

// coherent (agent / L2-bypassing) helpers ------------------------------------
DEV bf16x8 ldc16(const unsigned short* p) {              // 16B via 2 relaxed u64
  union { unsigned long long q[2]; bf16x8 v; } u;
  u.q[0] = __hip_atomic_load((const unsigned long long*)p,       __ATOMIC_RELAXED, __HIP_MEMORY_SCOPE_AGENT);
  u.q[1] = __hip_atomic_load((const unsigned long long*)(p + 4), __ATOMIC_RELAXED, __HIP_MEMORY_SCOPE_AGENT);
  return u.v;
}
DEV void stc16(unsigned short* p, unsigned short v) {
  __hip_atomic_store(p, v, __ATOMIC_RELAXED, __HIP_MEMORY_SCOPE_AGENT);
}

// hang-proof flag wait: all 64 lanes poll group's 32 words; sticky poison on
// timeout. No fence: consumer ordering comes from the branch dependency.
DEV void waitflag(int* flg, int grp, int tgt, int lane) {
  int* p = flg + grp * 32 + (lane & 31);
  int spins = 0;
  for (;;) {
    int v = __hip_atomic_load(p, __ATOMIC_RELAXED, __HIP_MEMORY_SCOPE_AGENT);
    if (__all(v >= tgt)) break;
    __builtin_amdgcn_s_sleep(2);
    if (++spins > (1 << 19)) {
      __hip_atomic_fetch_max(p, 0x40000000, __ATOMIC_RELAXED, __HIP_MEMORY_SCOPE_AGENT);
      break;
    }
  }
  asm volatile("" ::: "memory");
}

// ============================================================================
// Persistent forward recurrence. LDS = 128KB weight image only.
// ============================================================================
__global__ __launch_bounds__(256, 1) void gru_persistent(const float* __restrict__ x,
                                                         const float* __restrict__ bias,
                                                         unsigned char* __restrict__ ws) {
  __shared__ unsigned char lds[131072];
  const int tid = threadIdx.x, lane = tid & 63, wv = tid >> 6;
  const int bid = blockIdx.x;
  const int layer = bid >> 5, slice = bid & 31;
  const int l15 = lane & 15, q = lane >> 4;

  { // stage this block's 128KB weight image into LDS once
    const u32x4* src = (const u32x4*)(ws + OFF_WIMG + (size_t)(layer * 32 + slice) * WIMG_PER_LS);
    u32x4* dst = (u32x4*)lds;
    for (int i = tid; i < 8192; i += 256) dst[i] = src[i];
  }
  __syncthreads();

  // recurrent-side (Wh) hi B-fragments: 16 kk x 3 gates (compiler may cache)
  bf16x8 hB[48];
#pragma unroll
  for (int kk = 0; kk < 16; ++kk) {
    const int kg = kk * 4 + q;
    const unsigned char* wb = lds + 49152 + (size_t)kg * 768 + (size_t)l15 * 16;
    hB[kk * 3 + 0] = *(const bf16x8*)(wb);
    hB[kk * 3 + 1] = *(const bf16x8*)(wb + 256);
    hB[kk * 3 + 2] = *(const bf16x8*)(wb + 512);
  }

  unsigned short* h1 = (unsigned short*)(ws + OFF_H1);
  unsigned short* h2 = (unsigned short*)(ws + OFF_H2);
  int* flg = (int*)(ws + OFF_FLG);
  float* h2f = (float*)(ws + OFF_H2F);

  const int colg = slice * 16 + l15;
  const int row0 = wv * 16 + q * 4;            // first of this lane's 4 C rows
  const float b0 = bias[(size_t)(layer * 6 + 0) * 512 + colg];
  const float b1 = bias[(size_t)(layer * 6 + 1) * 512 + colg];
  const float b2 = bias[(size_t)(layer * 6 + 2) * 512 + colg];

  int* myflag = flg + layer * 32 + slice;
  f32x4 hprev{0.f, 0.f, 0.f, 0.f};

  if (layer == 0) {
    const float* xr0 = x + (size_t)(wv * 16 + l15) * Ss * Ii;   // this lane's A row
    for (int T = 1; T <= 1024; ++T) {
      // anti-dep (rarely binding): layer-2 consumed h1_{T-4}
      waitflag(flg, 1, T - 3, lane);
      f32x4 ax0{}, ax1{}, ax2{}, ah0{}, ah1{}, ah2{};
      // ---- x_t . Wi1 : A from global f32 (cached; hi/lo in-reg), B from LDS ----
      const float* xr = xr0 + (size_t)(T - 1) * Ii;
#pragma unroll 4
      for (int kk = 0; kk < 16; ++kk) {
        const int kg = kk * 4 + q;
        f32x4 va = *(const f32x4*)(xr + kg * 8);
        f32x4 vb = *(const f32x4*)(xr + kg * 8 + 4);
        bf16x8 ahi, alo;
#pragma unroll
        for (int e = 0; e < 4; ++e) {
          unsigned short ha = f2bf(va[e]);
          ((unsigned short*)&ahi)[e] = ha;
          ((unsigned short*)&alo)[e] = f2bf(va[e] - bf2f(ha));
          unsigned short hb_ = f2bf(vb[e]);
          ((unsigned short*)&ahi)[e + 4] = hb_;
          ((unsigned short*)&alo)[e + 4] = f2bf(vb[e] - bf2f(hb_));
        }
        const unsigned char* wb = lds + (size_t)kg * 768 + (size_t)l15 * 16;
        bf16x8 q0 = *(const bf16x8*)(wb);
        bf16x8 q1 = *(const bf16x8*)(wb + 256);
        bf16x8 q2 = *(const bf16x8*)(wb + 512);
        bf16x8 ql = *(const bf16x8*)(lds + 98304 + (size_t)kg * 256 + (size_t)l15 * 16);
        MFMA(ahi, q0, ax0); MFMA(alo, q0, ax0);
        MFMA(ahi, q1, ax1); MFMA(alo, q1, ax1);
        MFMA(ahi, q2, ax2); MFMA(alo, q2, ax2);
        MFMA(ahi, ql, ax2);
      }
      // ---- wait peers' h1_{T-1}, then coherent-load it; B from registers ----
      waitflag(flg, 0, T - 1, lane);
      const unsigned short* hsrc = h1 + (size_t)((T - 1) & 3) * 65536 + (size_t)(wv * 16 + l15) * 512;
#pragma unroll
      for (int kk = 0; kk < 16; ++kk) {
        const int kg = kk * 4 + q;
        bf16x8 ahi = ldc16(hsrc + kg * 8);
        bf16x8 alo = ldc16(hsrc + 32768 + kg * 8);
        bf16x8 ql = *(const bf16x8*)(lds + 98304 + 16384 + (size_t)kg * 256 + (size_t)l15 * 16);
        MFMA(ahi, hB[kk * 3 + 0], ah0); MFMA(alo, hB[kk * 3 + 0], ah0);
        MFMA(ahi, hB[kk * 3 + 1], ah1); MFMA(alo, hB[kk * 3 + 1], ah1);
        MFMA(ahi, hB[kk * 3 + 2], ah2); MFMA(alo, hB[kk * 3 + 2], ah2);
        MFMA(ahi, ql, ah2);
      }
      // ---- gates in-register; coherent-store h1_T ----
      unsigned short* hd = h1 + (size_t)(T & 3) * 65536;
#pragma unroll
      for (int e = 0; e < 4; ++e) {
        float rr = fsig(ax0[e] + ah0[e] + b0);
        float zz = fsig(ax1[e] + ah1[e] + b1);
        float nn = ftanh(ax2[e] + b2 + rr * ah2[e]);
        float hn = (1.f - zz) * nn + zz * hprev[e];
        hprev[e] = hn;
        unsigned short hi = f2bf(hn), lo = f2bf(hn - bf2f(hi));
        size_t o = (size_t)(row0 + e) * 512 + colg;
        stc16(hd + o, hi); stc16(hd + o + 32768, lo);
      }
      asm volatile("s_waitcnt vmcnt(0)" ::: "memory");     // h at coherence point
      __syncthreads();                                     // all waves done
      if (tid == 0)
        __hip_atomic_fetch_max(myflag, T, __ATOMIC_RELAXED, __HIP_MEMORY_SCOPE_AGENT);
    }
  } else {
    // layer 2, one step behind: at iter T computes h2_{T-1}
    for (int T = 2; T <= 1025; ++T) {
      f32x4 ax0{}, ax1{}, ax2{}, ah0{}, ah1{}, ah2{};
      // ---- peers' h2_{T-2} (usually ready): coherent loads, reg-B ----
      waitflag(flg, 1, T - 1, lane);
      const unsigned short* hsrc = h2 + (size_t)((T - 2) & 3) * 65536 + (size_t)(wv * 16 + l15) * 512;
#pragma unroll
      for (int kk = 0; kk < 16; ++kk) {
        const int kg = kk * 4 + q;
        bf16x8 ahi = ldc16(hsrc + kg * 8);
        bf16x8 alo = ldc16(hsrc + 32768 + kg * 8);
        bf16x8 ql = *(const bf16x8*)(lds + 98304 + 16384 + (size_t)kg * 256 + (size_t)l15 * 16);
        MFMA(ahi, hB[kk * 3 + 0], ah0); MFMA(alo, hB[kk * 3 + 0], ah0);
        MFMA(ahi, hB[kk * 3 + 1], ah1); MFMA(alo, hB[kk * 3 + 1], ah1);
        MFMA(ahi, hB[kk * 3 + 2], ah2); MFMA(alo, hB[kk * 3 + 2], ah2);
        MFMA(ahi, ql, ah2);
      }
      // ---- h1_{T-1} . Wi2 : the true critical path ----
      waitflag(flg, 0, T - 1, lane);
      const unsigned short* as = h1 + (size_t)((T - 1) & 3) * 65536 + (size_t)(wv * 16 + l15) * 512;
#pragma unroll 4
      for (int kk = 0; kk < 16; ++kk) {
        const int kg = kk * 4 + q;
        bf16x8 ahi = ldc16(as + kg * 8);
        bf16x8 alo = ldc16(as + 32768 + kg * 8);
        const unsigned char* wb = lds + (size_t)kg * 768 + (size_t)l15 * 16;
        bf16x8 q0 = *(const bf16x8*)(wb);
        bf16x8 q1 = *(const bf16x8*)(wb + 256);
        bf16x8 q2 = *(const bf16x8*)(wb + 512);
        bf16x8 ql = *(const bf16x8*)(lds + 98304 + (size_t)kg * 256 + (size_t)l15 * 16);
        MFMA(ahi, q0, ax0); MFMA(alo, q0, ax0);
        MFMA(ahi, q1, ax1); MFMA(alo, q1, ax1);
        MFMA(ahi, q2, ax2); MFMA(alo, q2, ax2);
        MFMA(ahi, ql, ax2);
      }
      unsigned short* hd = h2 + (size_t)((T - 1) & 3) * 65536;
#pragma unroll
      for (int e = 0; e < 4; ++e) {
        float rr = fsig(ax0[e] + ah0[e] + b0);
        float zz = fsig(ax1[e] + ah1[e] + b1);
        float nn = ftanh(ax2[e] + b2 + rr * ah2[e]);
        float hn = (1.f - zz) * nn + zz * hprev[e];
        hprev[e] = hn;
        unsigned short hi = f2bf(hn), lo = f2bf(hn - bf2f(hi));
        size_t o = (size_t)(row0 + e) * 512 + colg;
        stc16(hd + o, hi); stc16(hd + o + 32768, lo);
        if (T == 1025) h2f[o] = hn;
      }
      asm volatile("s_waitcnt vmcnt(0)" ::: "memory");
      __syncthreads();
      if (tid == 0)
        __hip_atomic_fetch_max(myflag, T, __ATOMIC_RELAXED, __HIP_MEMORY_SCOPE_AGENT);
    }
  }
}

// ============================================================================
// Backward direction, first scan step only (h0=0): out = (1-sig(xg1))*tanh(xg2).
// ============================================================================
__global__ __launch_bounds__(256) void gru_bstep(const float* __restrict__ inp, long rstride,
                                                 const float* __restrict__ Wi,
                                                 const float* __restrict__ bias,
                                                 float* __restrict__ out) {
  __shared__ float a[8192];                  // [16][512]
  int tid = threadIdx.x;
  int bg = blockIdx.x >> 4, cg = blockIdx.x & 15;
  for (int j = 0; j < 32; ++j) {
    int idx = j * 256 + tid;
    int r = idx >> 9, k = idx & 511;
    a[idx] = inp[(size_t)(bg * 16 + r) * rstride + k];
  }
  __syncthreads();
  int col = cg * 32 + (tid & 31);
  int r0 = tid >> 5;
  float z0 = bias[512 + col], z1 = z0;
  float n0 = bias[1024 + col], n1 = n0;
  const float* W1 = Wi + (size_t)512 * 512;
  const float* W2 = Wi + (size_t)2 * 512 * 512;
  for (int k = 0; k < 512; ++k) {
    float wz = W1[(size_t)k * 512 + col];
    float wn = W2[(size_t)k * 512 + col];
    float a0 = a[r0 * 512 + k], a1 = a[(r0 + 8) * 512 + k];
    z0 += a0 * wz; z1 += a1 * wz;
    n0 += a0 * wn; n1 += a1 * wn;
  }
  float s0 = fsig(z0), s1 = fsig(z1);
  out[(size_t)(bg * 16 + r0) * 512 + col]     = (1.f - s0) * ftanh(n0);
  out[(size_t)(bg * 16 + r0 + 8) * 512 + col] = (1.f - s1) * ftanh(n1);
}

__global__ __launch_bounds__(256) void fc_kernel(const float* __restrict__ h2f,
                                                 const float* __restrict__ hb2,
                                                 const float* __restrict__ fcw,
                                                 const float* __restrict__ fcb,
                                                 float* __restrict__ out) {
  __shared__ float a[16384];                 // [16][1024]
  int tid = threadIdx.x;
  int bg = blockIdx.x >> 4, cg = blockIdx.x & 15;
  for (int j = 0; j < 32; ++j) {
    int idx = j * 256 + tid;
    int r = idx >> 9, k = idx & 511;
    a[r * 1024 + k]       = h2f[(size_t)(bg * 16 + r) * 512 + k];
    a[r * 1024 + 512 + k] = hb2[(size_t)(bg * 16 + r) * 512 + k];
  }
  __syncthreads();
  int col = cg * 32 + (tid & 31);
  int r0 = tid >> 5;
  float s0 = fcb[col], s1 = fcb[col];
  for (int k = 0; k < 1024; ++k) {
    float wvv = fcw[(size_t)k * 512 + col];
    s0 += a[r0 * 1024 + k] * wvv;
    s1 += a[(r0 + 8) * 1024 + k] * wvv;
  }
  out[(size_t)(bg * 16 + r0) * 512 + col]     = s0;
  out[(size_t)(bg * 16 + r0 + 8) * 512 + col] = s1;
}

extern "C" void kernel_launch(void* const* d_in, const int* in_sizes, int n_in,
                              void* d_out, int out_size, void* d_ws, size_t ws_size,
                              hipStream_t stream) {
  const float* x   = (const float*)d_in[0];
  const float* Wi  = (const float*)d_in[1];
  const float* Wh  = (const float*)d_in[2];
  const float* b   = (const float*)d_in[3];
  const float* fcw = (const float*)d_in[4];
  const float* fcb = (const float*)d_in[5];
  float* out = (float*)d_out;
  unsigned char* ws = (unsigned char*)d_ws;
  if (ws_size < WS_NEED) return;   // visible failure (poisoned out), not corruption

  prep_weights<<<16384, 256, 0, stream>>>(Wi, Wh, (unsigned short*)(ws + OFF_WIMG));
  init_state<<<1024, 256, 0, stream>>>((uint32_t*)(ws + OFF_H1), (int*)(ws + OFF_FLG));
  gru_persistent<<<64, 256, 0, stream>>>(x, b, ws);
  gru_bstep<<<64, 256, 0, stream>>>(x + (size_t)1023 * 512, (long)Ss * Ii,
                                    Wi + (size_t)3 * 512 * 512, b + 3 * 512,
                                    (float*)(ws + OFF_HB1));
  gru_bstep<<<64, 256, 0, stream>>>((const float*)(ws + OFF_HB1), 512L,
                                    Wi + (size_t)9 * 512 * 512, b + 9 * 512,
                                    (float*)(ws + OFF_HB2));
  fc_kernel<<<64, 256, 0, stream>>>((const float*)(ws + OFF_H2F), (const float*)(ws + OFF_HB2),
                                    fcw, fcb, out);
}

// Round 5
// 15216.505 us; speedup vs baseline: 1.1247x; 1.1247x over previous
//
#include <hip/hip_runtime.h>
#include <cstdint>
#include <cmath>

// ============================================================================
// Bidirectional 2-layer GRU, B=64 S=1024 I=H=512, output = last-step concat @ fc.
//   forward : 1024-step recurrence, persistent kernel, 64 blocks (2 layers x
//             32 col-slices), block = 64 rows x 16 cols, gates in-register.
//   backward: only scan index 0 survives => ONE step per layer with h0=0.
//
// Round-5: decontended sync fabric.
//  - each flag in its own 64B line (flag i at int offset i*16)
//  - ONE combined poll per step, wave 0 only (lanes 0-31 -> group0 flags,
//    lanes 32-63 -> group1 flags), s_sleep(4) backoff, sticky timeout poison
//  - XCD-localized layers: layer = (bid%8)>=4 so each layer's 32-block sync
//    domain spans 4 XCDs instead of 8
//  - data path identical to round 3 (plain loads + acquire-inv by wave0;
//    plain stores + release-wbl2 by tid0) which validated at absmax 0.0078
// ============================================================================

typedef __attribute__((ext_vector_type(8))) short bf16x8;
typedef __attribute__((ext_vector_type(4))) float f32x4;
typedef __attribute__((ext_vector_type(4))) unsigned int u32x4;

#define DEV static __device__ __forceinline__

DEV unsigned short f2bf(float f) {
  union { float f; uint32_t u; } v; v.f = f;
  uint32_t u = v.u;
  return (unsigned short)((u + (((u >> 16) & 1u) + 0x7fffu)) >> 16);
}
DEV float bf2f(unsigned short h) {
  union { uint32_t u; float f; } v; v.u = ((uint32_t)h) << 16;
  return v.f;
}
DEV float fsig(float x)  { return 1.f / (1.f + __expf(-x)); }
DEV float ftanh(float x) { return 2.f / (1.f + __expf(-2.f * x)) - 1.f; }

static constexpr int Ss = 1024, Ii = 512;

// ---- workspace layout (bytes) ----
static constexpr size_t WIMG_PER_LS = 131072;                  // 96KB hi + 32KB n-lo
static constexpr size_t OFF_WIMG = 0;
static constexpr size_t WIMG_BYTES = (size_t)64 * WIMG_PER_LS; // 8 MB
static constexpr size_t OFF_H1  = OFF_WIMG + WIMG_BYTES;       // 4 planes x (hi|lo) [64][512] bf16
static constexpr size_t OFF_H2  = OFF_H1 + 524288;
static constexpr size_t OFF_FLG = OFF_H2 + 524288;             // int[64*16] (64B-padded flags)
static constexpr size_t OFF_H2F = OFF_FLG + 4096;              // f32 [64][512]
static constexpr size_t OFF_HB1 = OFF_H2F + 131072;
static constexpr size_t OFF_HB2 = OFF_HB1 + 131072;
static constexpr size_t WS_NEED = OFF_HB2 + 131072;

// ============================================================================
// Weight prep (layout unchanged): per (layer,slice) 65536 bf16:
//   [0,49152)     hi : m(2:Wi,Wh)*24576 + kg(64)*384 + (g*16+cc)*8 + kr(8)
//   [49152,65536) n-gate lo residual: m*8192 + kg*128 + cc*8 + kr
// ============================================================================
__global__ __launch_bounds__(256) void prep_weights(const float* __restrict__ Wi,
                                                    const float* __restrict__ Wh,
                                                    unsigned short* __restrict__ img) {
  uint32_t idx = blockIdx.x * 256 + threadIdx.x;          // < 4,194,304
  uint32_t ls = idx >> 16;                                // layer*32+slice
  uint32_t off = idx & 65535u;
  int l = (int)(ls >> 5), s = (int)(ls & 31);
  int m, g, cc, kg, kr;
  bool lo = off >= 49152u;
  if (!lo) {
    m = (int)(off / 24576u); uint32_t r = off % 24576u;
    kg = (int)(r / 384u); r %= 384u;
    int c = (int)(r >> 3); kr = (int)(r & 7u);
    g = c >> 4; cc = c & 15;
  } else {
    uint32_t o2 = off - 49152u;
    m = (int)(o2 >> 13); uint32_t r = o2 & 8191u;
    kg = (int)(r >> 7); r &= 127u;
    cc = (int)(r >> 3); kr = (int)(r & 7u);
    g = 2;
  }
  int h = s * 16 + cc, k = kg * 8 + kr;
  const float* W = m ? Wh : Wi;                           // [L][D][3][512][512], d=0
  float v = W[((size_t)(l * 6 + g) * 512 + k) * 512 + h];
  unsigned short hv = f2bf(v);
  if (lo) hv = f2bf(v - bf2f(hv));
  img[(size_t)ls * 65536 + off] = hv;
}

// zero h rings; flags at i*16: layer0 (i<32) = 0, layer1 = 1 (its step-1 is
// a virtual no-op)
__global__ __launch_bounds__(256) void init_state(uint32_t* __restrict__ hz,
                                                  int* __restrict__ flg) {
  int tid = blockIdx.x * 256 + threadIdx.x;
  if (tid < 262144) hz[tid] = 0u;                         // h1+h2 = 1MB
  if (tid < 1024) flg[tid] = ((tid & 15) == 0 && tid >= 512) ? 1 : 0;
}

#define MFMA(AA, BB, CC) CC = __builtin_amdgcn_mfma_f32_16x16x32_bf16(AA, BB, CC, 0, 0, 0)

// wave-0 combined wait: lane<32 polls group-0 flag[lane] >= tgtA, lane>=32
// polls group-1 flag[lane-32] >= tgtB. Each flag is on its own 64B line.
// Sticky timeout poison keeps everything hang-proof.
DEV void wait_combined(int* flg, int tgtA, int tgtB, int lane) {
  int* p = flg + lane * 16;
  const int tgt = (lane < 32) ? tgtA : tgtB;
  int spins = 0;
  for (;;) {
    int v = __hip_atomic_load(p, __ATOMIC_RELAXED, __HIP_MEMORY_SCOPE_AGENT);
    if (__all(v >= tgt)) break;
    __builtin_amdgcn_s_sleep(4);
    if (++spins > (1 << 17)) {
      __hip_atomic_fetch_max(p, 0x40000000, __ATOMIC_RELAXED, __HIP_MEMORY_SCOPE_AGENT);
      break;
    }
  }
}

// ============================================================================
// Persistent forward recurrence. LDS = 128KB weight image only.
// ============================================================================
__global__ __launch_bounds__(256, 1) void gru_persistent(const float* __restrict__ x,
                                                         const float* __restrict__ bias,
                                                         unsigned char* __restrict__ ws) {
  __shared__ unsigned char lds[131072];
  const int tid = threadIdx.x, lane = tid & 63, wv = tid >> 6;
  const int bid = blockIdx.x;
  // XCD-localized mapping (round-robin bid->XCD assumed): layer0 on XCD 0-3,
  // layer1 on XCD 4-7. Only affects performance, not correctness.
  const int xcd = bid & 7;
  const int layer = xcd >> 2;
  const int slice = (xcd & 3) * 8 + (bid >> 3);
  const int l15 = lane & 15, q = lane >> 4;

  { // stage this block's 128KB weight image into LDS once
    const u32x4* src = (const u32x4*)(ws + OFF_WIMG + (size_t)(layer * 32 + slice) * WIMG_PER_LS);
    u32x4* dst = (u32x4*)lds;
    for (int i = tid; i < 8192; i += 256) dst[i] = src[i];
  }
  __syncthreads();

  // recurrent-side (Wh) hi B-fragments: 16 kk x 3 gates (register-cached)
  bf16x8 hB[48];
#pragma unroll
  for (int kk = 0; kk < 16; ++kk) {
    const int kg = kk * 4 + q;
    const unsigned char* wb = lds + 49152 + (size_t)kg * 768 + (size_t)l15 * 16;
    hB[kk * 3 + 0] = *(const bf16x8*)(wb);
    hB[kk * 3 + 1] = *(const bf16x8*)(wb + 256);
    hB[kk * 3 + 2] = *(const bf16x8*)(wb + 512);
  }

  unsigned short* h1 = (unsigned short*)(ws + OFF_H1);
  unsigned short* h2 = (unsigned short*)(ws + OFF_H2);
  int* flg = (int*)(ws + OFF_FLG);
  float* h2f = (float*)(ws + OFF_H2F);

  const int colg = slice * 16 + l15;
  const int row0 = wv * 16 + q * 4;            // first of this lane's 4 C rows
  const float b0 = bias[(size_t)(layer * 6 + 0) * 512 + colg];
  const float b1 = bias[(size_t)(layer * 6 + 1) * 512 + colg];
  const float b2 = bias[(size_t)(layer * 6 + 2) * 512 + colg];

  int* myflag = flg + (layer * 32 + slice) * 16;
  f32x4 hprev{0.f, 0.f, 0.f, 0.f};

  if (layer == 0) {
    const float* xr0 = x + (size_t)(wv * 16 + l15) * Ss * Ii;   // this lane's A row
    for (int T = 1; T <= 1024; ++T) {
      f32x4 ax0{}, ax1{}, ax2{}, ah0{}, ah1{}, ah2{};
      // ---- x_t . Wi1 : A from global f32 (hi/lo in-reg), B from LDS ----
      const float* xr = xr0 + (size_t)(T - 1) * Ii;
#pragma unroll 4
      for (int kk = 0; kk < 16; ++kk) {
        const int kg = kk * 4 + q;
        f32x4 va = *(const f32x4*)(xr + kg * 8);
        f32x4 vb = *(const f32x4*)(xr + kg * 8 + 4);
        bf16x8 ahi, alo;
#pragma unroll
        for (int e = 0; e < 4; ++e) {
          unsigned short ha = f2bf(va[e]);
          ((unsigned short*)&ahi)[e] = ha;
          ((unsigned short*)&alo)[e] = f2bf(va[e] - bf2f(ha));
          unsigned short hb_ = f2bf(vb[e]);
          ((unsigned short*)&ahi)[e + 4] = hb_;
          ((unsigned short*)&alo)[e + 4] = f2bf(vb[e] - bf2f(hb_));
        }
        const unsigned char* wb = lds + (size_t)kg * 768 + (size_t)l15 * 16;
        bf16x8 q0 = *(const bf16x8*)(wb);
        bf16x8 q1 = *(const bf16x8*)(wb + 256);
        bf16x8 q2 = *(const bf16x8*)(wb + 512);
        bf16x8 ql = *(const bf16x8*)(lds + 98304 + (size_t)kg * 256 + (size_t)l15 * 16);
        MFMA(ahi, q0, ax0); MFMA(alo, q0, ax0);
        MFMA(ahi, q1, ax1); MFMA(alo, q1, ax1);
        MFMA(ahi, q2, ax2); MFMA(alo, q2, ax2);
        MFMA(ahi, ql, ax2);
      }
      // ---- combined wait: peers' h1_{T-1} ready AND layer-2 past h1_{T-4} ----
      if (wv == 0) {
        wait_combined(flg, T - 1, T - 3, lane);
        __builtin_amdgcn_fence(__ATOMIC_ACQUIRE, "agent");   // inv L1/L2 (CU/XCD-wide)
      }
      __syncthreads();
      // ---- h1_{T-1} . Wh1 : plain b128 loads (freshly invalidated), reg-B ----
      const unsigned short* hsrc = h1 + (size_t)((T - 1) & 3) * 65536 + (size_t)(wv * 16 + l15) * 512;
#pragma unroll
      for (int kk = 0; kk < 16; ++kk) {
        const int kg = kk * 4 + q;
        bf16x8 ahi = *(const bf16x8*)(hsrc + kg * 8);
        bf16x8 alo = *(const bf16x8*)(hsrc + 32768 + kg * 8);
        bf16x8 ql = *(const bf16x8*)(lds + 98304 + 16384 + (size_t)kg * 256 + (size_t)l15 * 16);
        MFMA(ahi, hB[kk * 3 + 0], ah0); MFMA(alo, hB[kk * 3 + 0], ah0);
        MFMA(ahi, hB[kk * 3 + 1], ah1); MFMA(alo, hB[kk * 3 + 1], ah1);
        MFMA(ahi, hB[kk * 3 + 2], ah2); MFMA(alo, hB[kk * 3 + 2], ah2);
        MFMA(ahi, ql, ah2);
      }
      // ---- gates in-register; store h1_T (plain stores -> L2 dirty) ----
      unsigned short* hd = h1 + (size_t)(T & 3) * 65536;
#pragma unroll
      for (int e = 0; e < 4; ++e) {
        float rr = fsig(ax0[e] + ah0[e] + b0);
        float zz = fsig(ax1[e] + ah1[e] + b1);
        float nn = ftanh(ax2[e] + b2 + rr * ah2[e]);
        float hn = (1.f - zz) * nn + zz * hprev[e];
        hprev[e] = hn;
        unsigned short hi = f2bf(hn), lo = f2bf(hn - bf2f(hi));
        size_t o = (size_t)(row0 + e) * 512 + colg;
        hd[o] = hi; hd[o + 32768] = lo;
      }
      __syncthreads();                          // all waves' stores complete
      if (tid == 0)                             // release: wbl2 then RMW
        __hip_atomic_fetch_max(myflag, T, __ATOMIC_RELEASE, __HIP_MEMORY_SCOPE_AGENT);
    }
  } else {
    // layer 2, one step behind: at iter T computes h2_{T-1}
    for (int T = 2; T <= 1025; ++T) {
      if (wv == 0) {
        wait_combined(flg, T - 1, T - 1, lane);
        __builtin_amdgcn_fence(__ATOMIC_ACQUIRE, "agent");
      }
      __syncthreads();
      f32x4 ax0{}, ax1{}, ax2{}, ah0{}, ah1{}, ah2{};
      // ---- h2_{T-2} . Wh2 : B from registers ----
      const unsigned short* hsrc = h2 + (size_t)((T - 2) & 3) * 65536 + (size_t)(wv * 16 + l15) * 512;
#pragma unroll
      for (int kk = 0; kk < 16; ++kk) {
        const int kg = kk * 4 + q;
        bf16x8 ahi = *(const bf16x8*)(hsrc + kg * 8);
        bf16x8 alo = *(const bf16x8*)(hsrc + 32768 + kg * 8);
        bf16x8 ql = *(const bf16x8*)(lds + 98304 + 16384 + (size_t)kg * 256 + (size_t)l15 * 16);
        MFMA(ahi, hB[kk * 3 + 0], ah0); MFMA(alo, hB[kk * 3 + 0], ah0);
        MFMA(ahi, hB[kk * 3 + 1], ah1); MFMA(alo, hB[kk * 3 + 1], ah1);
        MFMA(ahi, hB[kk * 3 + 2], ah2); MFMA(alo, hB[kk * 3 + 2], ah2);
        MFMA(ahi, ql, ah2);
      }
      // ---- h1_{T-1} . Wi2 : B from LDS ----
      const unsigned short* as = h1 + (size_t)((T - 1) & 3) * 65536 + (size_t)(wv * 16 + l15) * 512;
#pragma unroll 4
      for (int kk = 0; kk < 16; ++kk) {
        const int kg = kk * 4 + q;
        bf16x8 ahi = *(const bf16x8*)(as + kg * 8);
        bf16x8 alo = *(const bf16x8*)(as + 32768 + kg * 8);
        const unsigned char* wb = lds + (size_t)kg * 768 + (size_t)l15 * 16;
        bf16x8 q0 = *(const bf16x8*)(wb);
        bf16x8 q1 = *(const bf16x8*)(wb + 256);
        bf16x8 q2 = *(const bf16x8*)(wb + 512);
        bf16x8 ql = *(const bf16x8*)(lds + 98304 + (size_t)kg * 256 + (size_t)l15 * 16);
        MFMA(ahi, q0, ax0); MFMA(alo, q0, ax0);
        MFMA(ahi, q1, ax1); MFMA(alo, q1, ax1);
        MFMA(ahi, q2, ax2); MFMA(alo, q2, ax2);
        MFMA(ahi, ql, ax2);
      }
      unsigned short* hd = h2 + (size_t)((T - 1) & 3) * 65536;
#pragma unroll
      for (int e = 0; e < 4; ++e) {
        float rr = fsig(ax0[e] + ah0[e] + b0);
        float zz = fsig(ax1[e] + ah1[e] + b1);
        float nn = ftanh(ax2[e] + b2 + rr * ah2[e]);
        float hn = (1.f - zz) * nn + zz * hprev[e];
        hprev[e] = hn;
        unsigned short hi = f2bf(hn), lo = f2bf(hn - bf2f(hi));
        size_t o = (size_t)(row0 + e) * 512 + colg;
        hd[o] = hi; hd[o + 32768] = lo;
        if (T == 1025) h2f[o] = hn;
      }
      __syncthreads();
      if (tid == 0)
        __hip_atomic_fetch_max(myflag, T, __ATOMIC_RELEASE, __HIP_MEMORY_SCOPE_AGENT);
    }
  }
}

// ============================================================================
// Backward direction, first scan step only (h0=0): out = (1-sig(xg1))*tanh(xg2).
// ============================================================================
__global__ __launch_bounds__(256) void gru_bstep(const float* __restrict__ inp, long rstride,
                                                 const float* __restrict__ Wi,
                                                 const float* __restrict__ bias,
                                                 float* __restrict__ out) {
  __shared__ float a[8192];                  // [16][512]
  int tid = threadIdx.x;
  int bg = blockIdx.x >> 4, cg = blockIdx.x & 15;
  for (int j = 0; j < 32; ++j) {
    int idx = j * 256 + tid;
    int r = idx >> 9, k = idx & 511;
    a[idx] = inp[(size_t)(bg * 16 + r) * rstride + k];
  }
  __syncthreads();
  int col = cg * 32 + (tid & 31);
  int r0 = tid >> 5;
  float z0 = bias[512 + col], z1 = z0;
  float n0 = bias[1024 + col], n1 = n0;
  const float* W1 = Wi + (size_t)512 * 512;
  const float* W2 = Wi + (size_t)2 * 512 * 512;
  for (int k = 0; k < 512; ++k) {
    float wz = W1[(size_t)k * 512 + col];
    float wn = W2[(size_t)k * 512 + col];
    float a0 = a[r0 * 512 + k], a1 = a[(r0 + 8) * 512 + k];
    z0 += a0 * wz; z1 += a1 * wz;
    n0 += a0 * wn; n1 += a1 * wn;
  }
  float s0 = fsig(z0), s1 = fsig(z1);
  out[(size_t)(bg * 16 + r0) * 512 + col]     = (1.f - s0) * ftanh(n0);
  out[(size_t)(bg * 16 + r0 + 8) * 512 + col] = (1.f - s1) * ftanh(n1);
}

__global__ __launch_bounds__(256) void fc_kernel(const float* __restrict__ h2f,
                                                 const float* __restrict__ hb2,
                                                 const float* __restrict__ fcw,
                                                 const float* __restrict__ fcb,
                                                 float* __restrict__ out) {
  __shared__ float a[16384];                 // [16][1024]
  int tid = threadIdx.x;
  int bg = blockIdx.x >> 4, cg = blockIdx.x & 15;
  for (int j = 0; j < 32; ++j) {
    int idx = j * 256 + tid;
    int r = idx >> 9, k = idx & 511;
    a[r * 1024 + k]       = h2f[(size_t)(bg * 16 + r) * 512 + k];
    a[r * 1024 + 512 + k] = hb2[(size_t)(bg * 16 + r) * 512 + k];
  }
  __syncthreads();
  int col = cg * 32 + (tid & 31);
  int r0 = tid >> 5;
  float s0 = fcb[col], s1 = fcb[col];
  for (int k = 0; k < 1024; ++k) {
    float wvv = fcw[(size_t)k * 512 + col];
    s0 += a[r0 * 1024 + k] * wvv;
    s1 += a[(r0 + 8) * 1024 + k] * wvv;
  }
  out[(size_t)(bg * 16 + r0) * 512 + col]     = s0;
  out[(size_t)(bg * 16 + r0 + 8) * 512 + col] = s1;
}

extern "C" void kernel_launch(void* const* d_in, const int* in_sizes, int n_in,
                              void* d_out, int out_size, void* d_ws, size_t ws_size,
                              hipStream_t stream) {
  const float* x   = (const float*)d_in[0];
  const float* Wi  = (const float*)d_in[1];
  const float* Wh  = (const float*)d_in[2];
  const float* b   = (const float*)d_in[3];
  const float* fcw = (const float*)d_in[4];
  const float* fcb = (const float*)d_in[5];
  float* out = (float*)d_out;
  unsigned char* ws = (unsigned char*)d_ws;
  if (ws_size < WS_NEED) return;   // visible failure (poisoned out), not corruption

  prep_weights<<<16384, 256, 0, stream>>>(Wi, Wh, (unsigned short*)(ws + OFF_WIMG));
  init_state<<<1024, 256, 0, stream>>>((uint32_t*)(ws + OFF_H1), (int*)(ws + OFF_FLG));
  gru_persistent<<<64, 256, 0, stream>>>(x, b, ws);
  gru_bstep<<<64, 256, 0, stream>>>(x + (size_t)1023 * 512, (long)Ss * Ii,
                                    Wi + (size_t)3 * 512 * 512, b + 3 * 512,
                                    (float*)(ws + OFF_HB1));
  gru_bstep<<<64, 256, 0, stream>>>((const float*)(ws + OFF_HB1), 512L,
                                    Wi + (size_t)9 * 512 * 512, b + 9 * 512,
                                    (float*)(ws + OFF_HB2));
  fc_kernel<<<64, 256, 0, stream>>>((const float*)(ws + OFF_H2F), (const float*)(ws + OFF_HB2),
                                    fcw, fcb, out);
}

// Round 7
// 15209.326 us; speedup vs baseline: 1.1252x; 1.0005x over previous
//
#include <hip/hip_runtime.h>
#include <cstdint>
#include <cmath>

// ============================================================================
// Bidirectional 2-layer GRU, B=64 S=1024 I=H=512, output = last-step concat @ fc.
//   forward : 1024-step recurrence, persistent kernel, 64 worker blocks
//             (2 layers x 32 col-slices) + 192 HEATER blocks (DVFS experiment:
//             keep all CUs busy so clocks stay pinned; exit on completion flag).
//   backward: only scan index 0 survives => ONE step per layer with h0=0.
//
// Worker structure = round 5 exactly (validated absmax 0.0078):
//  - 64B-padded flags, wave-0 combined poll, sticky timeout poison
//  - plain loads + acquire fence; plain stores + release fetch_max
//  - 4-plane h rings; layer-2 one step behind layer-1
// ============================================================================

typedef __attribute__((ext_vector_type(8))) short bf16x8;
typedef __attribute__((ext_vector_type(4))) float f32x4;
typedef __attribute__((ext_vector_type(4))) unsigned int u32x4;

#define DEV static __device__ __forceinline__

DEV unsigned short f2bf(float f) {
  union { float f; uint32_t u; } v; v.f = f;
  uint32_t u = v.u;
  return (unsigned short)((u + (((u >> 16) & 1u) + 0x7fffu)) >> 16);
}
DEV float bf2f(unsigned short h) {
  union { uint32_t u; float f; } v; v.u = ((uint32_t)h) << 16;
  return v.f;
}
DEV float fsig(float x)  { return 1.f / (1.f + __expf(-x)); }
DEV float ftanh(float x) { return 2.f / (1.f + __expf(-2.f * x)) - 1.f; }

static constexpr int Ss = 1024, Ii = 512;

// ---- workspace layout (bytes) ----
static constexpr size_t WIMG_PER_LS = 131072;                  // 96KB hi + 32KB n-lo
static constexpr size_t OFF_WIMG = 0;
static constexpr size_t WIMG_BYTES = (size_t)64 * WIMG_PER_LS; // 8 MB
static constexpr size_t OFF_H1  = OFF_WIMG + WIMG_BYTES;       // 4 planes x (hi|lo) [64][512] bf16
static constexpr size_t OFF_H2  = OFF_H1 + 524288;
static constexpr size_t OFF_FLG = OFF_H2 + 524288;             // int[64*16] (64B-padded flags)
static constexpr size_t OFF_H2F = OFF_FLG + 4096;              // f32 [64][512]
static constexpr size_t OFF_HB1 = OFF_H2F + 131072;
static constexpr size_t OFF_HB2 = OFF_HB1 + 131072;
static constexpr size_t WS_NEED = OFF_HB2 + 131072;

// ============================================================================
// Weight prep (layout unchanged): per (layer,slice) 65536 bf16:
//   [0,49152)     hi : m(2:Wi,Wh)*24576 + kg(64)*384 + (g*16+cc)*8 + kr(8)
//   [49152,65536) n-gate lo residual: m*8192 + kg*128 + cc*8 + kr
// ============================================================================
__global__ __launch_bounds__(256) void prep_weights(const float* __restrict__ Wi,
                                                    const float* __restrict__ Wh,
                                                    unsigned short* __restrict__ img) {
  uint32_t idx = blockIdx.x * 256 + threadIdx.x;          // < 4,194,304
  uint32_t ls = idx >> 16;                                // layer*32+slice
  uint32_t off = idx & 65535u;
  int l = (int)(ls >> 5), s = (int)(ls & 31);
  int m, g, cc, kg, kr;
  bool lo = off >= 49152u;
  if (!lo) {
    m = (int)(off / 24576u); uint32_t r = off % 24576u;
    kg = (int)(r / 384u); r %= 384u;
    int c = (int)(r >> 3); kr = (int)(r & 7u);
    g = c >> 4; cc = c & 15;
  } else {
    uint32_t o2 = off - 49152u;
    m = (int)(o2 >> 13); uint32_t r = o2 & 8191u;
    kg = (int)(r >> 7); r &= 127u;
    cc = (int)(r >> 3); kr = (int)(r & 7u);
    g = 2;
  }
  int h = s * 16 + cc, k = kg * 8 + kr;
  const float* W = m ? Wh : Wi;                           // [L][D][3][512][512], d=0
  float v = W[((size_t)(l * 6 + g) * 512 + k) * 512 + h];
  unsigned short hv = f2bf(v);
  if (lo) hv = f2bf(v - bf2f(hv));
  img[(size_t)ls * 65536 + off] = hv;
}

// zero h rings; flags at i*16: layer0 (i<32) = 0, layer1 = 1 (its step-1 is
// a virtual no-op)
__global__ __launch_bounds__(256) void init_state(uint32_t* __restrict__ hz,
                                                  int* __restrict__ flg) {
  int tid = blockIdx.x * 256 + threadIdx.x;
  if (tid < 262144) hz[tid] = 0u;                         // h1+h2 = 1MB
  if (tid < 1024) flg[tid] = ((tid & 15) == 0 && tid >= 512) ? 1 : 0;
}

#define MFMA(AA, BB, CC) CC = __builtin_amdgcn_mfma_f32_16x16x32_bf16(AA, BB, CC, 0, 0, 0)

// wave-0 combined wait: lane<32 polls group-0 flag[lane] >= tgtA, lane>=32
// polls group-1 flag[lane-32] >= tgtB. Each flag on its own 64B line.
// Sticky timeout poison keeps everything hang-proof.
DEV void wait_combined(int* flg, int tgtA, int tgtB, int lane) {
  int* p = flg + lane * 16;
  const int tgt = (lane < 32) ? tgtA : tgtB;
  int spins = 0;
  for (;;) {
    int v = __hip_atomic_load(p, __ATOMIC_RELAXED, __HIP_MEMORY_SCOPE_AGENT);
    if (__all(v >= tgt)) break;
    __builtin_amdgcn_s_sleep(4);
    if (++spins > (1 << 17)) {
      __hip_atomic_fetch_max(p, 0x40000000, __ATOMIC_RELAXED, __HIP_MEMORY_SCOPE_AGENT);
      break;
    }
  }
}

// ============================================================================
// Persistent forward recurrence (bid<64) + clock-pinning heaters (bid>=64).
// LDS = 128KB weight image (workers only touch it).
// ============================================================================
__global__ __launch_bounds__(256, 1) void gru_persistent(const float* __restrict__ x,
                                                         const float* __restrict__ bias,
                                                         unsigned char* __restrict__ ws) {
  __shared__ unsigned char lds[131072];
  const int tid = threadIdx.x, lane = tid & 63, wv = tid >> 6;
  const int bid = blockIdx.x;
  int* flg = (int*)(ws + OFF_FLG);

  if (bid >= 64) {
    // ---- HEATER: dependent-FMA spin to hold clocks; exit when layer-2 done.
    // Busy% is what DVFS sees; dependent chain keeps power modest. Bounded
    // (1<<17 checks ~ 100ms) so it can never outlive a poisoned run for long.
    int* donep = flg + (32 + (bid & 31)) * 16;
    float a0 = 1.0f + (float)tid * 1e-6f;
    const float a1 = 1.0000001f, a2 = 1e-7f;
    for (int it = 0; it < (1 << 17); ++it) {
#pragma unroll 8
      for (int j = 0; j < 512; ++j) a0 = __builtin_fmaf(a0, a1, a2);
      asm volatile("" :: "v"(a0));                 // keep the chain live
      int v = __hip_atomic_load(donep, __ATOMIC_RELAXED, __HIP_MEMORY_SCOPE_AGENT);
      if (v >= 1025) break;
    }
    return;
  }

  // ---------------- workers: identical to round 5 ----------------
  const int xcd = bid & 7;
  const int layer = xcd >> 2;
  const int slice = (xcd & 3) * 8 + (bid >> 3);
  const int l15 = lane & 15, q = lane >> 4;

  { // stage this block's 128KB weight image into LDS once
    const u32x4* src = (const u32x4*)(ws + OFF_WIMG + (size_t)(layer * 32 + slice) * WIMG_PER_LS);
    u32x4* dst = (u32x4*)lds;
    for (int i = tid; i < 8192; i += 256) dst[i] = src[i];
  }
  __syncthreads();

  // recurrent-side (Wh) hi B-fragments: 16 kk x 3 gates (register-cached)
  bf16x8 hB[48];
#pragma unroll
  for (int kk = 0; kk < 16; ++kk) {
    const int kg = kk * 4 + q;
    const unsigned char* wb = lds + 49152 + (size_t)kg * 768 + (size_t)l15 * 16;
    hB[kk * 3 + 0] = *(const bf16x8*)(wb);
    hB[kk * 3 + 1] = *(const bf16x8*)(wb + 256);
    hB[kk * 3 + 2] = *(const bf16x8*)(wb + 512);
  }

  unsigned short* h1 = (unsigned short*)(ws + OFF_H1);
  unsigned short* h2 = (unsigned short*)(ws + OFF_H2);
  float* h2f = (float*)(ws + OFF_H2F);

  const int colg = slice * 16 + l15;
  const int row0 = wv * 16 + q * 4;            // first of this lane's 4 C rows
  const float b0 = bias[(size_t)(layer * 6 + 0) * 512 + colg];
  const float b1 = bias[(size_t)(layer * 6 + 1) * 512 + colg];
  const float b2 = bias[(size_t)(layer * 6 + 2) * 512 + colg];

  int* myflag = flg + (layer * 32 + slice) * 16;
  f32x4 hprev{0.f, 0.f, 0.f, 0.f};

  if (layer == 0) {
    const float* xr0 = x + (size_t)(wv * 16 + l15) * Ss * Ii;   // this lane's A row
    for (int T = 1; T <= 1024; ++T) {
      f32x4 ax0{}, ax1{}, ax2{}, ah0{}, ah1{}, ah2{};
      // ---- x_t . Wi1 : A from global f32 (hi/lo in-reg), B from LDS ----
      const float* xr = xr0 + (size_t)(T - 1) * Ii;
#pragma unroll 4
      for (int kk = 0; kk < 16; ++kk) {
        const int kg = kk * 4 + q;
        f32x4 va = *(const f32x4*)(xr + kg * 8);
        f32x4 vb = *(const f32x4*)(xr + kg * 8 + 4);
        bf16x8 ahi, alo;
#pragma unroll
        for (int e = 0; e < 4; ++e) {
          unsigned short ha = f2bf(va[e]);
          ((unsigned short*)&ahi)[e] = ha;
          ((unsigned short*)&alo)[e] = f2bf(va[e] - bf2f(ha));
          unsigned short hb_ = f2bf(vb[e]);
          ((unsigned short*)&ahi)[e + 4] = hb_;
          ((unsigned short*)&alo)[e + 4] = f2bf(vb[e] - bf2f(hb_));
        }
        const unsigned char* wb = lds + (size_t)kg * 768 + (size_t)l15 * 16;
        bf16x8 q0 = *(const bf16x8*)(wb);
        bf16x8 q1 = *(const bf16x8*)(wb + 256);
        bf16x8 q2 = *(const bf16x8*)(wb + 512);
        bf16x8 ql = *(const bf16x8*)(lds + 98304 + (size_t)kg * 256 + (size_t)l15 * 16);
        MFMA(ahi, q0, ax0); MFMA(alo, q0, ax0);
        MFMA(ahi, q1, ax1); MFMA(alo, q1, ax1);
        MFMA(ahi, q2, ax2); MFMA(alo, q2, ax2);
        MFMA(ahi, ql, ax2);
      }
      // ---- combined wait: peers' h1_{T-1} ready AND layer-2 past h1_{T-4} ----
      if (wv == 0) {
        wait_combined(flg, T - 1, T - 3, lane);
        __builtin_amdgcn_fence(__ATOMIC_ACQUIRE, "agent");   // inv L1/L2
      }
      __syncthreads();
      // ---- h1_{T-1} . Wh1 : plain b128 loads (freshly invalidated), reg-B ----
      const unsigned short* hsrc = h1 + (size_t)((T - 1) & 3) * 65536 + (size_t)(wv * 16 + l15) * 512;
#pragma unroll
      for (int kk = 0; kk < 16; ++kk) {
        const int kg = kk * 4 + q;
        bf16x8 ahi = *(const bf16x8*)(hsrc + kg * 8);
        bf16x8 alo = *(const bf16x8*)(hsrc + 32768 + kg * 8);
        bf16x8 ql = *(const bf16x8*)(lds + 98304 + 16384 + (size_t)kg * 256 + (size_t)l15 * 16);
        MFMA(ahi, hB[kk * 3 + 0], ah0); MFMA(alo, hB[kk * 3 + 0], ah0);
        MFMA(ahi, hB[kk * 3 + 1], ah1); MFMA(alo, hB[kk * 3 + 1], ah1);
        MFMA(ahi, hB[kk * 3 + 2], ah2); MFMA(alo, hB[kk * 3 + 2], ah2);
        MFMA(ahi, ql, ah2);
      }
      // ---- gates in-register; store h1_T ----
      unsigned short* hd = h1 + (size_t)(T & 3) * 65536;
#pragma unroll
      for (int e = 0; e < 4; ++e) {
        float rr = fsig(ax0[e] + ah0[e] + b0);
        float zz = fsig(ax1[e] + ah1[e] + b1);
        float nn = ftanh(ax2[e] + b2 + rr * ah2[e]);
        float hn = (1.f - zz) * nn + zz * hprev[e];
        hprev[e] = hn;
        unsigned short hi = f2bf(hn), lo = f2bf(hn - bf2f(hi));
        size_t o = (size_t)(row0 + e) * 512 + colg;
        hd[o] = hi; hd[o + 32768] = lo;
      }
      __syncthreads();                          // all waves' stores complete
      if (tid == 0)                             // release: wbl2 then RMW
        __hip_atomic_fetch_max(myflag, T, __ATOMIC_RELEASE, __HIP_MEMORY_SCOPE_AGENT);
    }
  } else {
    // layer 2, one step behind: at iter T computes h2_{T-1}
    for (int T = 2; T <= 1025; ++T) {
      if (wv == 0) {
        wait_combined(flg, T - 1, T - 1, lane);
        __builtin_amdgcn_fence(__ATOMIC_ACQUIRE, "agent");
      }
      __syncthreads();
      f32x4 ax0{}, ax1{}, ax2{}, ah0{}, ah1{}, ah2{};
      // ---- h2_{T-2} . Wh2 : B from registers ----
      const unsigned short* hsrc = h2 + (size_t)((T - 2) & 3) * 65536 + (size_t)(wv * 16 + l15) * 512;
#pragma unroll
      for (int kk = 0; kk < 16; ++kk) {
        const int kg = kk * 4 + q;
        bf16x8 ahi = *(const bf16x8*)(hsrc + kg * 8);
        bf16x8 alo = *(const bf16x8*)(hsrc + 32768 + kg * 8);
        bf16x8 ql = *(const bf16x8*)(lds + 98304 + 16384 + (size_t)kg * 256 + (size_t)l15 * 16);
        MFMA(ahi, hB[kk * 3 + 0], ah0); MFMA(alo, hB[kk * 3 + 0], ah0);
        MFMA(ahi, hB[kk * 3 + 1], ah1); MFMA(alo, hB[kk * 3 + 1], ah1);
        MFMA(ahi, hB[kk * 3 + 2], ah2); MFMA(alo, hB[kk * 3 + 2], ah2);
        MFMA(ahi, ql, ah2);
      }
      // ---- h1_{T-1} . Wi2 : B from LDS ----
      const unsigned short* as = h1 + (size_t)((T - 1) & 3) * 65536 + (size_t)(wv * 16 + l15) * 512;
#pragma unroll 4
      for (int kk = 0; kk < 16; ++kk) {
        const int kg = kk * 4 + q;
        bf16x8 ahi = *(const bf16x8*)(as + kg * 8);
        bf16x8 alo = *(const bf16x8*)(as + 32768 + kg * 8);
        const unsigned char* wb = lds + (size_t)kg * 768 + (size_t)l15 * 16;
        bf16x8 q0 = *(const bf16x8*)(wb);
        bf16x8 q1 = *(const bf16x8*)(wb + 256);
        bf16x8 q2 = *(const bf16x8*)(wb + 512);
        bf16x8 ql = *(const bf16x8*)(lds + 98304 + (size_t)kg * 256 + (size_t)l15 * 16);
        MFMA(ahi, q0, ax0); MFMA(alo, q0, ax0);
        MFMA(ahi, q1, ax1); MFMA(alo, q1, ax1);
        MFMA(ahi, q2, ax2); MFMA(alo, q2, ax2);
        MFMA(ahi, ql, ax2);
      }
      unsigned short* hd = h2 + (size_t)((T - 1) & 3) * 65536;
#pragma unroll
      for (int e = 0; e < 4; ++e) {
        float rr = fsig(ax0[e] + ah0[e] + b0);
        float zz = fsig(ax1[e] + ah1[e] + b1);
        float nn = ftanh(ax2[e] + b2 + rr * ah2[e]);
        float hn = (1.f - zz) * nn + zz * hprev[e];
        hprev[e] = hn;
        unsigned short hi = f2bf(hn), lo = f2bf(hn - bf2f(hi));
        size_t o = (size_t)(row0 + e) * 512 + colg;
        hd[o] = hi; hd[o + 32768] = lo;
        if (T == 1025) h2f[o] = hn;
      }
      __syncthreads();
      if (tid == 0)
        __hip_atomic_fetch_max(myflag, T, __ATOMIC_RELEASE, __HIP_MEMORY_SCOPE_AGENT);
    }
  }
}

// ============================================================================
// Backward direction, first scan step only (h0=0): out = (1-sig(xg1))*tanh(xg2).
// ============================================================================
__global__ __launch_bounds__(256) void gru_bstep(const float* __restrict__ inp, long rstride,
                                                 const float* __restrict__ Wi,
                                                 const float* __restrict__ bias,
                                                 float* __restrict__ out) {
  __shared__ float a[8192];                  // [16][512]
  int tid = threadIdx.x;
  int bg = blockIdx.x >> 4, cg = blockIdx.x & 15;
  for (int j = 0; j < 32; ++j) {
    int idx = j * 256 + tid;
    int r = idx >> 9, k = idx & 511;
    a[idx] = inp[(size_t)(bg * 16 + r) * rstride + k];
  }
  __syncthreads();
  int col = cg * 32 + (tid & 31);
  int r0 = tid >> 5;
  float z0 = bias[512 + col], z1 = z0;
  float n0 = bias[1024 + col], n1 = n0;
  const float* W1 = Wi + (size_t)512 * 512;
  const float* W2 = Wi + (size_t)2 * 512 * 512;
  for (int k = 0; k < 512; ++k) {
    float wz = W1[(size_t)k * 512 + col];
    float wn = W2[(size_t)k * 512 + col];
    float a0 = a[r0 * 512 + k], a1 = a[(r0 + 8) * 512 + k];
    z0 += a0 * wz; z1 += a1 * wz;
    n0 += a0 * wn; n1 += a1 * wn;
  }
  float s0 = fsig(z0), s1 = fsig(z1);
  out[(size_t)(bg * 16 + r0) * 512 + col]     = (1.f - s0) * ftanh(n0);
  out[(size_t)(bg * 16 + r0 + 8) * 512 + col] = (1.f - s1) * ftanh(n1);
}

__global__ __launch_bounds__(256) void fc_kernel(const float* __restrict__ h2f,
                                                 const float* __restrict__ hb2,
                                                 const float* __restrict__ fcw,
                                                 const float* __restrict__ fcb,
                                                 float* __restrict__ out) {
  __shared__ float a[16384];                 // [16][1024]
  int tid = threadIdx.x;
  int bg = blockIdx.x >> 4, cg = blockIdx.x & 15;
  for (int j = 0; j < 32; ++j) {
    int idx = j * 256 + tid;
    int r = idx >> 9, k = idx & 511;
    a[r * 1024 + k]       = h2f[(size_t)(bg * 16 + r) * 512 + k];
    a[r * 1024 + 512 + k] = hb2[(size_t)(bg * 16 + r) * 512 + k];
  }
  __syncthreads();
  int col = cg * 32 + (tid & 31);
  int r0 = tid >> 5;
  float s0 = fcb[col], s1 = fcb[col];
  for (int k = 0; k < 1024; ++k) {
    float wvv = fcw[(size_t)k * 512 + col];
    s0 += a[r0 * 1024 + k] * wvv;
    s1 += a[(r0 + 8) * 1024 + k] * wvv;
  }
  out[(size_t)(bg * 16 + r0) * 512 + col]     = s0;
  out[(size_t)(bg * 16 + r0 + 8) * 512 + col] = s1;
}

extern "C" void kernel_launch(void* const* d_in, const int* in_sizes, int n_in,
                              void* d_out, int out_size, void* d_ws, size_t ws_size,
                              hipStream_t stream) {
  const float* x   = (const float*)d_in[0];
  const float* Wi  = (const float*)d_in[1];
  const float* Wh  = (const float*)d_in[2];
  const float* b   = (const float*)d_in[3];
  const float* fcw = (const float*)d_in[4];
  const float* fcb = (const float*)d_in[5];
  float* out = (float*)d_out;
  unsigned char* ws = (unsigned char*)d_ws;
  if (ws_size < WS_NEED) return;   // visible failure (poisoned out), not corruption

  prep_weights<<<16384, 256, 0, stream>>>(Wi, Wh, (unsigned short*)(ws + OFF_WIMG));
  init_state<<<1024, 256, 0, stream>>>((uint32_t*)(ws + OFF_H1), (int*)(ws + OFF_FLG));
  gru_persistent<<<256, 256, 0, stream>>>(x, b, ws);
  gru_bstep<<<64, 256, 0, stream>>>(x + (size_t)1023 * 512, (long)Ss * Ii,
                                    Wi + (size_t)3 * 512 * 512, b + 3 * 512,
                                    (float*)(ws + OFF_HB1));
  gru_bstep<<<64, 256, 0, stream>>>((const float*)(ws + OFF_HB1), 512L,
                                    Wi + (size_t)9 * 512 * 512, b + 9 * 512,
                                    (float*)(ws + OFF_HB2));
  fc_kernel<<<64, 256, 0, stream>>>((const float*)(ws + OFF_H2F), (const float*)(ws + OFF_HB2),
                                    fcw, fcb, out);
}

// Round 8
// 13741.704 us; speedup vs baseline: 1.2454x; 1.1068x over previous
//
#include <hip/hip_runtime.h>
#include <cstdint>
#include <cmath>

// ============================================================================
// Bidirectional 2-layer GRU, B=64 S=1024 I=H=512, output = last-step concat @ fc.
//   forward : 1024-step recurrence, persistent kernel, 64 blocks (2 layers x
//             32 col-slices), block = 64 rows x 16 cols, gates in-register.
//   backward: only scan index 0 survives => ONE step per layer with h0=0.
//
// Round-8: ZERO cache-maintenance ops in the loop. All cross-block traffic
// (h planes, flags) uses plain inline-asm sc0|sc1 ops that go directly to the
// memory-side coherence point: no wbl2, no inv, no atomics, no fences.
// (Theory: rounds 2-5 all kept release/acquire cache ops on the critical path;
// a 4MB-L2 wbl2 tag-scan per step explains the invariant ~17us/step.)
// h loads are pipelined dwordx4 sc0sc1 with counted vmcnt(8), every gap walled
// by sched_barrier(0) so compiler VMEM can't break the counts (rule #18).
// Producer: sc0sc1 stores -> vmcnt(0) -> syncthreads -> sc0sc1 flag store.
// Consumer: wave-0 combined poll (branch dependency orders the data loads).
// Hang-proof: per-wave alive-latch timeout -> bounded free-run, never hangs.
// ============================================================================

typedef __attribute__((ext_vector_type(8))) short bf16x8;
typedef __attribute__((ext_vector_type(4))) float f32x4;
typedef __attribute__((ext_vector_type(4))) unsigned int u32x4;

#define DEV static __device__ __forceinline__

DEV unsigned short f2bf(float f) {
  union { float f; uint32_t u; } v; v.f = f;
  uint32_t u = v.u;
  return (unsigned short)((u + (((u >> 16) & 1u) + 0x7fffu)) >> 16);
}
DEV float bf2f(unsigned short h) {
  union { uint32_t u; float f; } v; v.u = ((uint32_t)h) << 16;
  return v.f;
}
DEV float fsig(float x)  { return 1.f / (1.f + __expf(-x)); }
DEV float ftanh(float x) { return 2.f / (1.f + __expf(-2.f * x)) - 1.f; }

static constexpr int Ss = 1024, Ii = 512;

// ---- workspace layout (bytes) ----
static constexpr size_t WIMG_PER_LS = 131072;                  // 96KB hi + 32KB n-lo
static constexpr size_t OFF_WIMG = 0;
static constexpr size_t WIMG_BYTES = (size_t)64 * WIMG_PER_LS; // 8 MB
static constexpr size_t OFF_H1  = OFF_WIMG + WIMG_BYTES;       // 4 planes x 128KB (hi | lo at +64KB)
static constexpr size_t OFF_H2  = OFF_H1 + 524288;
static constexpr size_t OFF_FLG = OFF_H2 + 524288;             // int[64*16] (64B-padded flags)
static constexpr size_t OFF_H2F = OFF_FLG + 4096;              // f32 [64][512]
static constexpr size_t OFF_HB1 = OFF_H2F + 131072;
static constexpr size_t OFF_HB2 = OFF_HB1 + 131072;
static constexpr size_t WS_NEED = OFF_HB2 + 131072;

// ============================================================================
// Weight prep (layout unchanged): per (layer,slice) 65536 bf16:
//   [0,49152)     hi : m(2:Wi,Wh)*24576 + kg(64)*384 + (g*16+cc)*8 + kr(8)
//   [49152,65536) n-gate lo residual: m*8192 + kg*128 + cc*8 + kr
// ============================================================================
__global__ __launch_bounds__(256) void prep_weights(const float* __restrict__ Wi,
                                                    const float* __restrict__ Wh,
                                                    unsigned short* __restrict__ img) {
  uint32_t idx = blockIdx.x * 256 + threadIdx.x;          // < 4,194,304
  uint32_t ls = idx >> 16;                                // layer*32+slice
  uint32_t off = idx & 65535u;
  int l = (int)(ls >> 5), s = (int)(ls & 31);
  int m, g, cc, kg, kr;
  bool lo = off >= 49152u;
  if (!lo) {
    m = (int)(off / 24576u); uint32_t r = off % 24576u;
    kg = (int)(r / 384u); r %= 384u;
    int c = (int)(r >> 3); kr = (int)(r & 7u);
    g = c >> 4; cc = c & 15;
  } else {
    uint32_t o2 = off - 49152u;
    m = (int)(o2 >> 13); uint32_t r = o2 & 8191u;
    kg = (int)(r >> 7); r &= 127u;
    cc = (int)(r >> 3); kr = (int)(r & 7u);
    g = 2;
  }
  int h = s * 16 + cc, k = kg * 8 + kr;
  const float* W = m ? Wh : Wi;                           // [L][D][3][512][512], d=0
  float v = W[((size_t)(l * 6 + g) * 512 + k) * 512 + h];
  unsigned short hv = f2bf(v);
  if (lo) hv = f2bf(v - bf2f(hv));
  img[(size_t)ls * 65536 + off] = hv;
}

// zero h rings; flags at i*16: layer0 (i<32) = 0, layer1 = 1
__global__ __launch_bounds__(256) void init_state(uint32_t* __restrict__ hz,
                                                  int* __restrict__ flg) {
  int tid = blockIdx.x * 256 + threadIdx.x;
  if (tid < 262144) hz[tid] = 0u;                         // h1+h2 = 1MB
  if (tid < 1024) flg[tid] = ((tid & 15) == 0 && tid >= 512) ? 1 : 0;
}

#define MFMA(AA, BB, CC) CC = __builtin_amdgcn_mfma_f32_16x16x32_bf16(AA, BB, CC, 0, 0, 0)
#define SB0 __builtin_amdgcn_sched_barrier(0)
#define VMWAIT0 asm volatile("s_waitcnt vmcnt(0)" ::: "memory")
#define VMWAIT8 asm volatile("s_waitcnt vmcnt(8)" ::: "memory")
// coherence-point-direct (no L1/L2 allocation, no cache maintenance) ops
#define LD16CP(dst, addr) \
  asm volatile("global_load_dwordx4 %0, %1, off sc0 sc1" : "=&v"(dst) : "v"((const void*)(addr)))
#define ST2CP(addr, val) \
  asm volatile("global_store_short %0, %1, off sc0 sc1" :: "v"((void*)(addr)), "v"((uint32_t)(val)) : "memory")
#define ST4CP(addr, val) \
  asm volatile("global_store_dword %0, %1, off sc0 sc1" :: "v"((void*)(addr)), "v"(val) : "memory")

DEV int pollcp(const int* p) {
  int v;
  asm volatile("global_load_dword %0, %1, off sc0 sc1\ns_waitcnt vmcnt(0)"
               : "=v"(v) : "v"((const void*)p) : "memory");
  return v;
}

// wave-0 combined wait: lane<32 polls layer0 flag[lane] >= tgtA, lane>=32
// polls layer1 flag[lane-32] >= tgtB. Alive-latch timeout: first timeout
// ~0.13s, thereafter 64 spins -> bounded free-run, never hangs.
DEV void wait_combined(int* flg, int tgtA, int tgtB, int lane, int& alive) {
  const int* p = flg + lane * 16;
  const int tgt = (lane < 32) ? tgtA : tgtB;
  const int lim = alive ? (1 << 17) : 64;
  int spins = 0;
  for (;;) {
    int v = pollcp(p);
    if (__all(v >= tgt)) break;
    __builtin_amdgcn_s_sleep(1);
    if (++spins > lim) { alive = 0; break; }
  }
}

// issue 8 pipelined 16B loads: 4 (hi,lo) pairs at BOFF + 64*j (+65536 for lo)
#define ISSUE8(R, ABASE, BOFF)                                                 \
  _Pragma("unroll")                                                            \
  for (int j = 0; j < 4; ++j) {                                                \
    LD16CP(R[2*j],   (ABASE) + (BOFF) + 64 * j);                               \
    LD16CP(R[2*j+1], (ABASE) + (BOFF) + 64 * j + 65536);                       \
  }
// consume 4 (hi,lo) fragment pairs, B from hB registers (+ n-lo from LDS)
#define MFB_REG(R, b, A0, A1, A2)                                              \
  _Pragma("unroll")                                                            \
  for (int j = 0; j < 4; ++j) {                                                \
    const int kk = 4 * (b) + j;                                                \
    const int kg = 16 * (b) + 4 * j + q;                                       \
    bf16x8 ql = *(const bf16x8*)(lds + 98304 + 16384 + (size_t)kg * 256 + (size_t)l15 * 16); \
    MFMA(R[2*j], hB[kk*3+0], A0); MFMA(R[2*j+1], hB[kk*3+0], A0);              \
    MFMA(R[2*j], hB[kk*3+1], A1); MFMA(R[2*j+1], hB[kk*3+1], A1);              \
    MFMA(R[2*j], hB[kk*3+2], A2); MFMA(R[2*j+1], hB[kk*3+2], A2);              \
    MFMA(R[2*j], ql, A2);                                                      \
  }
// consume 4 pairs, B (Wi) from LDS
#define MFB_LDSB(R, b, A0, A1, A2)                                             \
  _Pragma("unroll")                                                            \
  for (int j = 0; j < 4; ++j) {                                                \
    const int kg = 16 * (b) + 4 * j + q;                                       \
    const unsigned char* wb = lds + (size_t)kg * 768 + (size_t)l15 * 16;       \
    bf16x8 q0 = *(const bf16x8*)(wb);                                          \
    bf16x8 q1 = *(const bf16x8*)(wb + 256);                                    \
    bf16x8 q2 = *(const bf16x8*)(wb + 512);                                    \
    bf16x8 ql = *(const bf16x8*)(lds + 98304 + (size_t)kg * 256 + (size_t)l15 * 16); \
    MFMA(R[2*j], q0, A0); MFMA(R[2*j+1], q0, A0);                              \
    MFMA(R[2*j], q1, A1); MFMA(R[2*j+1], q1, A1);                              \
    MFMA(R[2*j], q2, A2); MFMA(R[2*j+1], q2, A2);                              \
    MFMA(R[2*j], ql, A2);                                                      \
  }
// full pipelined [16,512]@[512,48] hi/lo GEMM, A via sc0sc1, SB0-walled
#define HGEMM(ABASE, MFB, A0, A1, A2)                                          \
  {                                                                            \
    bf16x8 fa[8], fb[8];                                                       \
    SB0; ISSUE8(fa, ABASE, 0)  SB0; ISSUE8(fb, ABASE, 256) SB0;                \
    VMWAIT8; SB0; MFB(fa, 0, A0, A1, A2) SB0;                                  \
    ISSUE8(fa, ABASE, 512) SB0; VMWAIT8; SB0; MFB(fb, 1, A0, A1, A2) SB0;      \
    ISSUE8(fb, ABASE, 768) SB0; VMWAIT8; SB0; MFB(fa, 2, A0, A1, A2) SB0;      \
    VMWAIT0; SB0; MFB(fb, 3, A0, A1, A2) SB0;                                  \
  }
// x_t . Wi1 : plain cached loads (read-only x), hi/lo built in-reg, B from LDS
#define XGEMM(T0)                                                              \
  {                                                                            \
    const float* xr = xr0 + (size_t)(T0) * Ii;                                 \
    _Pragma("unroll 4")                                                        \
    for (int kk = 0; kk < 16; ++kk) {                                          \
      const int kg = kk * 4 + q;                                               \
      f32x4 va = *(const f32x4*)(xr + kg * 8);                                 \
      f32x4 vb = *(const f32x4*)(xr + kg * 8 + 4);                             \
      bf16x8 ahi, alo;                                                         \
      _Pragma("unroll")                                                        \
      for (int e = 0; e < 4; ++e) {                                            \
        unsigned short ha = f2bf(va[e]);                                       \
        ((unsigned short*)&ahi)[e] = ha;                                       \
        ((unsigned short*)&alo)[e] = f2bf(va[e] - bf2f(ha));                   \
        unsigned short hb_ = f2bf(vb[e]);                                      \
        ((unsigned short*)&ahi)[e + 4] = hb_;                                  \
        ((unsigned short*)&alo)[e + 4] = f2bf(vb[e] - bf2f(hb_));              \
      }                                                                        \
      const unsigned char* wb = lds + (size_t)kg * 768 + (size_t)l15 * 16;     \
      bf16x8 q0 = *(const bf16x8*)(wb);                                        \
      bf16x8 q1 = *(const bf16x8*)(wb + 256);                                  \
      bf16x8 q2 = *(const bf16x8*)(wb + 512);                                  \
      bf16x8 ql = *(const bf16x8*)(lds + 98304 + (size_t)kg * 256 + (size_t)l15 * 16); \
      MFMA(ahi, q0, ax0); MFMA(alo, q0, ax0);                                  \
      MFMA(ahi, q1, ax1); MFMA(alo, q1, ax1);                                  \
      MFMA(ahi, q2, ax2); MFMA(alo, q2, ax2);                                  \
      MFMA(ahi, ql, ax2);                                                      \
    }                                                                          \
  }

// ============================================================================
// Persistent forward recurrence. LDS = 128KB weight image only.
// ============================================================================
__global__ __launch_bounds__(256, 1) void gru_persistent(const float* __restrict__ x,
                                                         const float* __restrict__ bias,
                                                         unsigned char* __restrict__ ws) {
  __shared__ unsigned char lds[131072];
  const int tid = threadIdx.x, lane = tid & 63, wv = tid >> 6;
  const int bid = blockIdx.x;
  const int xcd = bid & 7;
  const int layer = xcd >> 2;
  const int slice = (xcd & 3) * 8 + (bid >> 3);
  const int l15 = lane & 15, q = lane >> 4;

  { // stage this block's 128KB weight image into LDS once
    const u32x4* src = (const u32x4*)(ws + OFF_WIMG + (size_t)(layer * 32 + slice) * WIMG_PER_LS);
    u32x4* dst = (u32x4*)lds;
    for (int i = tid; i < 8192; i += 256) dst[i] = src[i];
  }
  __syncthreads();

  // recurrent-side (Wh) hi B-fragments: 16 kk x 3 gates
  bf16x8 hB[48];
#pragma unroll
  for (int kk = 0; kk < 16; ++kk) {
    const int kg = kk * 4 + q;
    const unsigned char* wb = lds + 49152 + (size_t)kg * 768 + (size_t)l15 * 16;
    hB[kk * 3 + 0] = *(const bf16x8*)(wb);
    hB[kk * 3 + 1] = *(const bf16x8*)(wb + 256);
    hB[kk * 3 + 2] = *(const bf16x8*)(wb + 512);
  }

  unsigned char* h1b = ws + OFF_H1;
  unsigned char* h2b = ws + OFF_H2;
  int* flg = (int*)(ws + OFF_FLG);
  float* h2f = (float*)(ws + OFF_H2F);

  const int colg = slice * 16 + l15;
  const int row0 = wv * 16 + q * 4;            // first of this lane's 4 C rows
  const int arow = wv * 16 + l15;              // this lane's A row
  const float b0 = bias[(size_t)(layer * 6 + 0) * 512 + colg];
  const float b1 = bias[(size_t)(layer * 6 + 1) * 512 + colg];
  const float b2 = bias[(size_t)(layer * 6 + 2) * 512 + colg];

  int* myflag = flg + (layer * 32 + slice) * 16;
  f32x4 hprev{0.f, 0.f, 0.f, 0.f};
  int alive = 1;

  if (layer == 0) {
    const float* xr0 = x + (size_t)arow * Ss * Ii;
    f32x4 ax0{}, ax1{}, ax2{};
    XGEMM(0)                                   // prologue: x_0 . Wi1
    for (int T = 1; T <= 1024; ++T) {
      // wait: peers' h1_{T-1} ready AND layer-2 past h1_{T-4} (plane reuse)
      if (wv == 0) wait_combined(flg, T - 1, T - 3, lane, alive);
      __syncthreads();
      f32x4 ah0{}, ah1{}, ah2{};
      const unsigned char* ab = h1b + (size_t)((T - 1) & 3) * 131072 + (size_t)arow * 1024 + (size_t)q * 16;
      HGEMM(ab, MFB_REG, ah0, ah1, ah2)
      // gates in-register; sc0sc1 store h1_T
      unsigned char* hd = h1b + (size_t)(T & 3) * 131072;
#pragma unroll
      for (int e = 0; e < 4; ++e) {
        float rr = fsig(ax0[e] + ah0[e] + b0);
        float zz = fsig(ax1[e] + ah1[e] + b1);
        float nn = ftanh(ax2[e] + b2 + rr * ah2[e]);
        float hn = (1.f - zz) * nn + zz * hprev[e];
        hprev[e] = hn;
        unsigned short hi = f2bf(hn), lo = f2bf(hn - bf2f(hi));
        size_t ob = (size_t)(row0 + e) * 1024 + (size_t)colg * 2;
        ST2CP(hd + ob, hi); ST2CP(hd + ob + 65536, lo);
      }
      VMWAIT0;                                 // stores acked at coherence point
      __syncthreads();                         // all waves done
      if (tid == 0) ST4CP(myflag, T);
      // next step's x GEMM (plain loads, outside the counted-vmcnt region)
      ax0 = f32x4{}; ax1 = f32x4{}; ax2 = f32x4{};
      if (T < 1024) XGEMM(T)
    }
  } else {
    // layer 2, one step behind: at iter T computes h2_{T-1}
    for (int T = 2; T <= 1025; ++T) {
      if (wv == 0) wait_combined(flg, T - 1, T - 1, lane, alive);
      __syncthreads();
      f32x4 ax0{}, ax1{}, ax2{}, ah0{}, ah1{}, ah2{};
      const unsigned char* ab2 = h2b + (size_t)((T - 2) & 3) * 131072 + (size_t)arow * 1024 + (size_t)q * 16;
      HGEMM(ab2, MFB_REG, ah0, ah1, ah2)       // h2_{T-2} . Wh2
      const unsigned char* ab1 = h1b + (size_t)((T - 1) & 3) * 131072 + (size_t)arow * 1024 + (size_t)q * 16;
      HGEMM(ab1, MFB_LDSB, ax0, ax1, ax2)      // h1_{T-1} . Wi2
      unsigned char* hd = h2b + (size_t)((T - 1) & 3) * 131072;
#pragma unroll
      for (int e = 0; e < 4; ++e) {
        float rr = fsig(ax0[e] + ah0[e] + b0);
        float zz = fsig(ax1[e] + ah1[e] + b1);
        float nn = ftanh(ax2[e] + b2 + rr * ah2[e]);
        float hn = (1.f - zz) * nn + zz * hprev[e];
        hprev[e] = hn;
        unsigned short hi = f2bf(hn), lo = f2bf(hn - bf2f(hi));
        size_t ob = (size_t)(row0 + e) * 1024 + (size_t)colg * 2;
        ST2CP(hd + ob, hi); ST2CP(hd + ob + 65536, lo);
        if (T == 1025) h2f[(size_t)(row0 + e) * 512 + colg] = hn;
      }
      VMWAIT0;
      __syncthreads();
      if (tid == 0) ST4CP(myflag, T);
    }
  }
}

// ============================================================================
// Backward direction, first scan step only (h0=0): out = (1-sig(xg1))*tanh(xg2).
// ============================================================================
__global__ __launch_bounds__(256) void gru_bstep(const float* __restrict__ inp, long rstride,
                                                 const float* __restrict__ Wi,
                                                 const float* __restrict__ bias,
                                                 float* __restrict__ out) {
  __shared__ float a[8192];                  // [16][512]
  int tid = threadIdx.x;
  int bg = blockIdx.x >> 4, cg = blockIdx.x & 15;
  for (int j = 0; j < 32; ++j) {
    int idx = j * 256 + tid;
    int r = idx >> 9, k = idx & 511;
    a[idx] = inp[(size_t)(bg * 16 + r) * rstride + k];
  }
  __syncthreads();
  int col = cg * 32 + (tid & 31);
  int r0 = tid >> 5;
  float z0 = bias[512 + col], z1 = z0;
  float n0 = bias[1024 + col], n1 = n0;
  const float* W1 = Wi + (size_t)512 * 512;
  const float* W2 = Wi + (size_t)2 * 512 * 512;
  for (int k = 0; k < 512; ++k) {
    float wz = W1[(size_t)k * 512 + col];
    float wn = W2[(size_t)k * 512 + col];
    float a0 = a[r0 * 512 + k], a1 = a[(r0 + 8) * 512 + k];
    z0 += a0 * wz; z1 += a1 * wz;
    n0 += a0 * wn; n1 += a1 * wn;
  }
  float s0 = fsig(z0), s1 = fsig(z1);
  out[(size_t)(bg * 16 + r0) * 512 + col]     = (1.f - s0) * ftanh(n0);
  out[(size_t)(bg * 16 + r0 + 8) * 512 + col] = (1.f - s1) * ftanh(n1);
}

__global__ __launch_bounds__(256) void fc_kernel(const float* __restrict__ h2f,
                                                 const float* __restrict__ hb2,
                                                 const float* __restrict__ fcw,
                                                 const float* __restrict__ fcb,
                                                 float* __restrict__ out) {
  __shared__ float a[16384];                 // [16][1024]
  int tid = threadIdx.x;
  int bg = blockIdx.x >> 4, cg = blockIdx.x & 15;
  for (int j = 0; j < 32; ++j) {
    int idx = j * 256 + tid;
    int r = idx >> 9, k = idx & 511;
    a[r * 1024 + k]       = h2f[(size_t)(bg * 16 + r) * 512 + k];
    a[r * 1024 + 512 + k] = hb2[(size_t)(bg * 16 + r) * 512 + k];
  }
  __syncthreads();
  int col = cg * 32 + (tid & 31);
  int r0 = tid >> 5;
  float s0 = fcb[col], s1 = fcb[col];
  for (int k = 0; k < 1024; ++k) {
    float wvv = fcw[(size_t)k * 512 + col];
    s0 += a[r0 * 1024 + k] * wvv;
    s1 += a[(r0 + 8) * 1024 + k] * wvv;
  }
  out[(size_t)(bg * 16 + r0) * 512 + col]     = s0;
  out[(size_t)(bg * 16 + r0 + 8) * 512 + col] = s1;
}

extern "C" void kernel_launch(void* const* d_in, const int* in_sizes, int n_in,
                              void* d_out, int out_size, void* d_ws, size_t ws_size,
                              hipStream_t stream) {
  const float* x   = (const float*)d_in[0];
  const float* Wi  = (const float*)d_in[1];
  const float* Wh  = (const float*)d_in[2];
  const float* b   = (const float*)d_in[3];
  const float* fcw = (const float*)d_in[4];
  const float* fcb = (const float*)d_in[5];
  float* out = (float*)d_out;
  unsigned char* ws = (unsigned char*)d_ws;
  if (ws_size < WS_NEED) return;   // visible failure (poisoned out), not corruption

  prep_weights<<<16384, 256, 0, stream>>>(Wi, Wh, (unsigned short*)(ws + OFF_WIMG));
  init_state<<<1024, 256, 0, stream>>>((uint32_t*)(ws + OFF_H1), (int*)(ws + OFF_FLG));
  gru_persistent<<<64, 256, 0, stream>>>(x, b, ws);
  gru_bstep<<<64, 256, 0, stream>>>(x + (size_t)1023 * 512, (long)Ss * Ii,
                                    Wi + (size_t)3 * 512 * 512, b + 3 * 512,
                                    (float*)(ws + OFF_HB1));
  gru_bstep<<<64, 256, 0, stream>>>((const float*)(ws + OFF_HB1), 512L,
                                    Wi + (size_t)9 * 512 * 512, b + 9 * 512,
                                    (float*)(ws + OFF_HB2));
  fc_kernel<<<64, 256, 0, stream>>>((const float*)(ws + OFF_H2F), (const float*)(ws + OFF_HB2),
                                    fcw, fcb, out);
}